// Round 2
// baseline (334.490 us; speedup 1.0000x reference)
//
#include <hip/hip_runtime.h>

typedef __bf16 bf16_t;
typedef __bf16 bf16x8 __attribute__((ext_vector_type(8)));
typedef __bf16 bf16x4 __attribute__((ext_vector_type(4)));
typedef float  f32x4  __attribute__((ext_vector_type(4)));

#define LOG2E 1.44269504088896340736f

// ---------------------------------------------------------------- helpers
__device__ __forceinline__ void gload_lds16(const void* g, void* l) {
  __builtin_amdgcn_global_load_lds(
      (const __attribute__((address_space(1))) void*)g,
      (__attribute__((address_space(3))) void*)l, 16, 0, 0);
}

__device__ __forceinline__ void store_c(float* p, float v)  { *p = v; }
__device__ __forceinline__ void store_c(bf16_t* p, float v) { *p = (bf16_t)v; }

// ---------------------------------------------------------------- cast fp32 -> bf16
__global__ __launch_bounds__(256) void cast_kernel(const float* __restrict__ in,
                                                   bf16_t* __restrict__ out, int n4) {
  int i = blockIdx.x * 256 + threadIdx.x;
  const int stride = gridDim.x * 256;
  for (; i < n4; i += stride) {
    f32x4 v = *(const f32x4*)(in + (size_t)i * 4);
    bf16x4 o;
#pragma unroll
    for (int j = 0; j < 4; ++j) o[j] = (bf16_t)v[j];
    *(bf16x4*)(out + (size_t)i * 4) = o;
  }
}

// ---------------------------------------------------------------- GEMM  C[M][N] = A[M][K] * B[N][K]^T
// 128x128 tile, BK=32, 256 threads (4 waves, 2x2), global_load_lds staging.
template <typename OutT>
__global__ __launch_bounds__(256) void gemm_bt(const bf16_t* __restrict__ A,
                                               const bf16_t* __restrict__ B,
                                               OutT* __restrict__ C,
                                               int M, int N, int K) {
  __shared__ bf16_t As[128 * 32];
  __shared__ bf16_t Bs[128 * 32];
  const int tid  = threadIdx.x;
  const int lane = tid & 63;
  const int wid  = tid >> 6;
  const int wm = wid >> 1, wn = wid & 1;
  const size_t m0 = (size_t)blockIdx.y * 128;
  const size_t n0 = (size_t)blockIdx.x * 128;

  f32x4 acc[4][4] = {};

  for (int k0 = 0; k0 < K; k0 += 32) {
#pragma unroll
    for (int j = 0; j < 2; ++j) {
      const int c = tid + j * 256;          // 512 16B chunks per tile
      const int r = c >> 2;
      const int kp = (c & 3) * 8;
      gload_lds16(A + (m0 + r) * K + k0 + kp, As + (size_t)c * 8);
      gload_lds16(B + (n0 + r) * K + k0 + kp, Bs + (size_t)c * 8);
    }
    __syncthreads();

    const int kk = (lane >> 4) * 8;
    const int rs = lane & 15;
    bf16x8 af[4], bfv[4];
#pragma unroll
    for (int t = 0; t < 4; ++t) {
      af[t]  = *(const bf16x8*)(As + (wm * 64 + t * 16 + rs) * 32 + kk);
      bfv[t] = *(const bf16x8*)(Bs + (wn * 64 + t * 16 + rs) * 32 + kk);
    }
#pragma unroll
    for (int mt = 0; mt < 4; ++mt)
#pragma unroll
      for (int nt = 0; nt < 4; ++nt)
        acc[mt][nt] = __builtin_amdgcn_mfma_f32_16x16x32_bf16(af[mt], bfv[nt], acc[mt][nt], 0, 0, 0);
    __syncthreads();
  }

#pragma unroll
  for (int mt = 0; mt < 4; ++mt)
#pragma unroll
    for (int nt = 0; nt < 4; ++nt)
#pragma unroll
      for (int r = 0; r < 4; ++r) {
        size_t row = m0 + wm * 64 + mt * 16 + (lane >> 4) * 4 + r;
        size_t col = n0 + wn * 64 + nt * 16 + (lane & 15);
        store_c(C + row * N + col, acc[mt][nt][r]);
      }
}

// ---------------------------------------------------------------- RoPE + reorg
// qkv[b][s][3072] -> Q[b][h][s][64], K[b][h][s][64] (rotary applied), Vt[b][h][64][S]
__global__ __launch_bounds__(256) void rope_reorg(const bf16_t* __restrict__ qkv,
                                                  const float* __restrict__ cosT,
                                                  const float* __restrict__ sinT,
                                                  bf16_t* __restrict__ Q,
                                                  bf16_t* __restrict__ Kd,
                                                  bf16_t* __restrict__ Vt) {
  __shared__ bf16_t T[64 * 72];
  const int blk  = blockIdx.x;
  const int sblk = blk & 31;
  const int hh   = (blk >> 5) % 48;
  const int b    = blk / (32 * 48);
  const int s0   = sblk * 64;
  const int tid  = threadIdx.x;

  if (hh < 32) {
    const bool isq = hh < 16;
    const int h = isq ? hh : hh - 16;
    bf16_t* dst = (isq ? Q : Kd) + (size_t)(b * 16 + h) * 2048 * 64;
    for (int u = tid; u < 512; u += 256) {
      const int s = u >> 3, oct = u & 7;
      const size_t src = ((size_t)(b * 2048) + s0 + s) * 3072 + hh * 64;
      bf16x8 x = *(const bf16x8*)(qkv + src + oct * 8);
      bf16x8 y = *(const bf16x8*)(qkv + src + ((oct * 8) ^ 32));
      const float* cp = cosT + (size_t)(s0 + s) * 64 + oct * 8;
      const float* sp = sinT + (size_t)(s0 + s) * 64 + oct * 8;
      const float sgn = (oct < 4) ? -1.f : 1.f;
      bf16x8 ov;
#pragma unroll
      for (int j = 0; j < 8; ++j) {
        float xv = (float)x[j], yv = (float)y[j];
        ov[j] = (bf16_t)(xv * cp[j] + sgn * yv * sp[j]);
      }
      *(bf16x8*)(dst + (size_t)(s0 + s) * 64 + oct * 8) = ov;
    }
  } else {
    const int hv = hh - 32;
    for (int u = tid; u < 512; u += 256) {
      const int s = u >> 3, oct = u & 7;
      *(bf16x8*)(&T[s * 72 + oct * 8]) =
          *(const bf16x8*)(qkv + ((size_t)(b * 2048) + s0 + s) * 3072 + hh * 64 + oct * 8);
    }
    __syncthreads();
    bf16_t* dst = Vt + (size_t)(b * 16 + hv) * 64 * 2048;
    for (int u = tid; u < 512; u += 256) {
      const int d = u >> 3, soct = u & 7;
      bf16x8 w;
#pragma unroll
      for (int j = 0; j < 8; ++j) w[j] = T[(soct * 8 + j) * 72 + d];
      *(bf16x8*)(dst + (size_t)d * 2048 + s0 + soct * 8) = w;
    }
  }
}

// ---------------------------------------------------------------- flash attention (causal)
// Q,K: [b][h][s][64]  Vt: [b][h][64][S]  O: [b][s][h*64+d]  (bf16)
__global__ __launch_bounds__(256) void attn_kernel(const bf16_t* __restrict__ Q,
                                                   const bf16_t* __restrict__ Kt,
                                                   const bf16_t* __restrict__ Vt,
                                                   bf16_t* __restrict__ O) {
  const int qblk = blockIdx.x;
  const int h    = blockIdx.y;
  const int b    = blockIdx.z;
  const int tid  = threadIdx.x;
  const int lane = tid & 63;
  const int wid  = tid >> 6;
  const int bh   = b * 16 + h;
  const bf16_t* Qb = Q  + (size_t)bh * 2048 * 64;
  const bf16_t* Kb = Kt + (size_t)bh * 2048 * 64;
  const bf16_t* Vb = Vt + (size_t)bh * 64 * 2048;

  // padded strides: all ds_read_b128 patterns are <=2-way bank conflicts (free)
  __shared__ bf16_t Ks[32 * 72];       // K tile  [32 keys][64 d], stride 72
  __shared__ bf16_t Vs[64 * 56];       // Vt tile [64 d][32 keys], stride 56
  __shared__ bf16_t Ps[4][16 * 40];    // per-wave P tile [16 q][32 k], stride 40

  const int q0  = qblk * 64 + wid * 16;
  const int l15 = lane & 15;
  const int dd  = (lane >> 4) * 8;

  bf16x8 qf0 = *(const bf16x8*)(Qb + (size_t)(q0 + l15) * 64 + dd);
  bf16x8 qf1 = *(const bf16x8*)(Qb + (size_t)(q0 + l15) * 64 + 32 + dd);

  f32x4 o[4] = {};
  float mr[4], lr[4];
#pragma unroll
  for (int r = 0; r < 4; ++r) { mr[r] = -3.0e38f; lr[r] = 0.f; }

  const int nkv = qblk * 64 + 64;
  const int ks_row = tid >> 3, ks_oct = tid & 7;
  const int vs_row = tid >> 2, vs_oct = tid & 3;

  for (int kv0 = 0; kv0 < nkv; kv0 += 32) {
    // cooperative staging (coalesced)
    *(bf16x8*)(Ks + ks_row * 72 + ks_oct * 8) =
        *(const bf16x8*)(Kb + (size_t)(kv0 + ks_row) * 64 + ks_oct * 8);
    *(bf16x8*)(Vs + vs_row * 56 + vs_oct * 8) =
        *(const bf16x8*)(Vb + (size_t)vs_row * 2048 + kv0 + vs_oct * 8);
    __syncthreads();

    // S = Q K^T  (two 16-key column tiles)
    f32x4 st[2] = {};
#pragma unroll
    for (int kt = 0; kt < 2; ++kt) {
      bf16x8 kf0 = *(const bf16x8*)(Ks + (kt * 16 + l15) * 72 + dd);
      bf16x8 kf1 = *(const bf16x8*)(Ks + (kt * 16 + l15) * 72 + 32 + dd);
      st[kt] = __builtin_amdgcn_mfma_f32_16x16x32_bf16(qf0, kf0, st[kt], 0, 0, 0);
      st[kt] = __builtin_amdgcn_mfma_f32_16x16x32_bf16(qf1, kf1, st[kt], 0, 0, 0);
    }

    float p[2][4];
    const bool need_mask = (kv0 + 31 > q0);
#pragma unroll
    for (int kt = 0; kt < 2; ++kt)
#pragma unroll
      for (int r = 0; r < 4; ++r) {
        float v = st[kt][r] * 0.125f;   // 1/sqrt(64)
        if (need_mask) {
          int kg = kv0 + kt * 16 + l15;
          int qg = q0 + (lane >> 4) * 4 + r;
          if (kg > qg) v = -3.0e38f;
        }
        p[kt][r] = v;
      }

    // online softmax: row stats live in the 16-lane group (masks 1,2,4,8)
    float al[4];
#pragma unroll
    for (int r = 0; r < 4; ++r) {
      float mb = fmaxf(p[0][r], p[1][r]);
      mb = fmaxf(mb, __shfl_xor(mb, 1));
      mb = fmaxf(mb, __shfl_xor(mb, 2));
      mb = fmaxf(mb, __shfl_xor(mb, 4));
      mb = fmaxf(mb, __shfl_xor(mb, 8));
      float mn = fmaxf(mr[r], mb);
      al[r] = exp2f((mr[r] - mn) * LOG2E);
      float s0 = exp2f((p[0][r] - mn) * LOG2E);
      float s1 = exp2f((p[1][r] - mn) * LOG2E);
      p[0][r] = s0; p[1][r] = s1;
      float lb = s0 + s1;
      lb += __shfl_xor(lb, 1);
      lb += __shfl_xor(lb, 2);
      lb += __shfl_xor(lb, 4);
      lb += __shfl_xor(lb, 8);
      lr[r] = lr[r] * al[r] + lb;
      mr[r] = mn;
    }
#pragma unroll
    for (int dt = 0; dt < 4; ++dt)
#pragma unroll
      for (int r = 0; r < 4; ++r) o[dt][r] *= al[r];

    // P -> LDS (re-layout C-frag -> A-frag), per-wave private tile
#pragma unroll
    for (int kt = 0; kt < 2; ++kt)
#pragma unroll
      for (int r = 0; r < 4; ++r)
        Ps[wid][((lane >> 4) * 4 + r) * 40 + kt * 16 + l15] = (bf16_t)p[kt][r];

    asm volatile("s_waitcnt lgkmcnt(0)" ::: "memory");
    __builtin_amdgcn_sched_barrier(0);

    bf16x8 pa = *(const bf16x8*)(&Ps[wid][l15 * 40 + dd]);
#pragma unroll
    for (int dt = 0; dt < 4; ++dt) {
      bf16x8 vf = *(const bf16x8*)(Vs + (dt * 16 + l15) * 56 + dd);
      o[dt] = __builtin_amdgcn_mfma_f32_16x16x32_bf16(pa, vf, o[dt], 0, 0, 0);
    }
    __syncthreads();
  }

#pragma unroll
  for (int r = 0; r < 4; ++r) {
    float inv = 1.f / lr[r];
    size_t srow = (size_t)b * 2048 + q0 + (lane >> 4) * 4 + r;
#pragma unroll
    for (int dt = 0; dt < 4; ++dt)
      O[srow * 1024 + h * 64 + dt * 16 + l15] = (bf16_t)(o[dt][r] * inv);
  }
}

// ---------------------------------------------------------------- launch
extern "C" void kernel_launch(void* const* d_in, const int* in_sizes, int n_in,
                              void* d_out, int out_size, void* d_ws, size_t ws_size,
                              hipStream_t stream) {
  const float* hs   = (const float*)d_in[0];   // [2][2048][1024]
  const float* cosT = (const float*)d_in[1];   // [2048][64]
  const float* sinT = (const float*)d_in[2];   // [2048][64]
  const float* wqkv = (const float*)d_in[3];   // [3072][1024]
  const float* wo   = (const float*)d_in[4];   // [1024][1024]
  float* out = (float*)d_out;                  // [2][2048][1024]

  char* ws = (char*)d_ws;
  bf16_t* hs_b   = (bf16_t*)(ws);                     //  8,388,608 B
  bf16_t* wqkv_b = (bf16_t*)(ws + 8388608);           //  6,291,456 B
  bf16_t* wo_b   = (bf16_t*)(ws + 14680064);          //  2,097,152 B
  bf16_t* qkv    = (bf16_t*)(ws + 16777216);          // 25,165,824 B
  bf16_t* Qb     = (bf16_t*)(ws + 41943040);          //  8,388,608 B
  bf16_t* Kb     = (bf16_t*)(ws + 50331648);          //  8,388,608 B
  bf16_t* Vtb    = (bf16_t*)(ws + 58720256);          //  8,388,608 B
  bf16_t* aout   = (bf16_t*)(ws + 67108864);          //  8,388,608 B

  cast_kernel<<<2048, 256, 0, stream>>>(hs,   hs_b,   4194304 / 4);
  cast_kernel<<<1024, 256, 0, stream>>>(wqkv, wqkv_b, 3145728 / 4);
  cast_kernel<<<512,  256, 0, stream>>>(wo,   wo_b,   1048576 / 4);

  gemm_bt<bf16_t><<<dim3(24, 32), 256, 0, stream>>>(hs_b, wqkv_b, qkv, 4096, 3072, 1024);

  rope_reorg<<<3072, 256, 0, stream>>>(qkv, cosT, sinT, Qb, Kb, Vtb);

  attn_kernel<<<dim3(32, 16, 2), 256, 0, stream>>>(Qb, Kb, Vtb, aout);

  gemm_bt<float><<<dim3(8, 32), 256, 0, stream>>>(aout, wo_b, out, 4096, 1024, 1024);
}